// Round 1
// baseline (8192.678 us; speedup 1.0000x reference)
//
#include <hip/hip_runtime.h>
#include <cmath>

// Problem constants
#define Bb   64
#define Tt   128
#define Dd   2048
#define Hh   512
#define Gg   2048      // 4*H
#define Cc   101
#define ROWS 8192      // B*T

// ---------------- SGEMM (fp32, vector ALU) ----------------
// C[M,N] = A[M,K] @ B[K,N] + bias[N]
// 128x128 tile, BK=8, 256 threads, 8x8 per thread.
#define BM 128
#define BN 128
#define BK 8

__global__ __launch_bounds__(256)
void sgemm_bias(const float* __restrict__ A, const float* __restrict__ B,
                const float* __restrict__ bias, float* __restrict__ C,
                int M, int N, int K) {
  __shared__ float As[BK][BM];
  __shared__ float Bs[BK][BN];
  const int tid  = threadIdx.x;
  const int bn   = blockIdx.x;
  const int bm   = blockIdx.y;
  const int row0 = bm * BM, col0 = bn * BN;
  const int tr = (tid >> 4) << 3;   // (tid/16)*8
  const int tc = (tid & 15) << 3;   // (tid%16)*8

  float acc[8][8];
#pragma unroll
  for (int i = 0; i < 8; ++i)
#pragma unroll
    for (int j = 0; j < 8; ++j) acc[i][j] = 0.f;

  const int arow = tid >> 1;          // 0..127
  const int acol = (tid & 1) << 2;    // 0 or 4
  const int brow = tid >> 5;          // 0..7
  const int bcol = (tid & 31) << 2;   // 0..124
  const float* Ap = A + (size_t)(row0 + arow) * K + acol;
  const float* Bp = B + (size_t)brow * N + (col0 + bcol);

  for (int k0 = 0; k0 < K; k0 += BK) {
    const float4 av = *(const float4*)(Ap + k0);
    const float4 bv = *(const float4*)(Bp + (size_t)k0 * N);
    As[acol + 0][arow] = av.x;
    As[acol + 1][arow] = av.y;
    As[acol + 2][arow] = av.z;
    As[acol + 3][arow] = av.w;
    *(float4*)(&Bs[brow][bcol]) = bv;
    __syncthreads();
#pragma unroll
    for (int k = 0; k < BK; ++k) {
      float a[8], b[8];
      *(float4*)(a)     = *(const float4*)(&As[k][tr]);
      *(float4*)(a + 4) = *(const float4*)(&As[k][tr + 4]);
      *(float4*)(b)     = *(const float4*)(&Bs[k][tc]);
      *(float4*)(b + 4) = *(const float4*)(&Bs[k][tc + 4]);
#pragma unroll
      for (int i = 0; i < 8; ++i)
#pragma unroll
        for (int j = 0; j < 8; ++j)
          acc[i][j] = fmaf(a[i], b[j], acc[i][j]);
    }
    __syncthreads();
  }

  float bj[8];
#pragma unroll
  for (int j = 0; j < 8; ++j) bj[j] = bias[col0 + tc + j];
#pragma unroll
  for (int i = 0; i < 8; ++i) {
    float* Cp = C + (size_t)(row0 + tr + i) * N + (col0 + tc);
    float4 o0, o1;
    o0.x = acc[i][0] + bj[0]; o0.y = acc[i][1] + bj[1];
    o0.z = acc[i][2] + bj[2]; o0.w = acc[i][3] + bj[3];
    o1.x = acc[i][4] + bj[4]; o1.y = acc[i][5] + bj[5];
    o1.z = acc[i][6] + bj[6]; o1.w = acc[i][7] + bj[7];
    *(float4*)(Cp)     = o0;
    *(float4*)(Cp + 4) = o1;
  }
}

// ---------------- LSTM recurrent step ----------------
// gates = pre[row(t)] + h[t-1] @ Wh ; elementwise LSTM update.
// grid = 128 blocks (16 b-groups x 8 m-groups), 256 threads = [4 b x 64 m],
// each thread computes all 4 gates of one (b, m).
__global__ __launch_bounds__(256)
void lstm_step(const float* __restrict__ pre, const float* __restrict__ Wh,
               float* __restrict__ h_all, float* __restrict__ c_state,
               int t) {
  const int ml = threadIdx.x & 63;
  const int bl = threadIdx.x >> 6;      // 0..3
  const int mg = blockIdx.x & 7;        // 0..7
  const int bg = blockIdx.x >> 3;       // 0..15
  const int m = mg * 64 + ml;           // 0..511
  const int b = bg * 4 + bl;            // 0..63

  float ai = 0.f, aj = 0.f, af = 0.f, ao = 0.f;
  if (t > 0) {
    const float* hrow = h_all + ((size_t)b * Tt + (t - 1)) * Hh;
    const float* W = Wh + m;
#pragma unroll 2
    for (int r = 0; r < Hh; r += 4) {
      const float4 hv = *(const float4*)(hrow + r);
      const float* w = W + (size_t)r * Gg;
      ai = fmaf(hv.x, w[0], ai);    aj = fmaf(hv.x, w[512], aj);
      af = fmaf(hv.x, w[1024], af); ao = fmaf(hv.x, w[1536], ao);
      w += Gg;
      ai = fmaf(hv.y, w[0], ai);    aj = fmaf(hv.y, w[512], aj);
      af = fmaf(hv.y, w[1024], af); ao = fmaf(hv.y, w[1536], ao);
      w += Gg;
      ai = fmaf(hv.z, w[0], ai);    aj = fmaf(hv.z, w[512], aj);
      af = fmaf(hv.z, w[1024], af); ao = fmaf(hv.z, w[1536], ao);
      w += Gg;
      ai = fmaf(hv.w, w[0], ai);    aj = fmaf(hv.w, w[512], aj);
      af = fmaf(hv.w, w[1024], af); ao = fmaf(hv.w, w[1536], ao);
    }
  }
  const size_t prow = ((size_t)b * Tt + t) * (size_t)Gg + m;
  const float gi = pre[prow]        + ai;
  const float gj = pre[prow + 512]  + aj;
  const float gf = pre[prow + 1024] + af;
  const float go = pre[prow + 1536] + ao;
  const float cp = (t > 0) ? c_state[b * Hh + m] : 0.f;
  const float si = 1.f / (1.f + expf(-gi));
  const float sf = 1.f / (1.f + expf(-(gf + 1.f)));   // forget bias 1.0
  const float so = 1.f / (1.f + expf(-go));
  const float nc = fmaf(cp, sf, si * tanhf(gj));
  const float nh = tanhf(nc) * so;
  c_state[b * Hh + m] = nc;
  h_all[((size_t)b * Tt + t) * Hh + m] = nh;
}

// ---------------- Output projection + softmax + CE ----------------
// Block handles 8 rows; threads 0..100 each own one class column.
__global__ __launch_bounds__(128)
void proj_softmax(const float* __restrict__ h2, const float* __restrict__ Wout,
                  const float* __restrict__ bout, const int* __restrict__ labels,
                  float* __restrict__ preds, float* __restrict__ ce) {
  __shared__ float hs[8][Hh];
  __shared__ float red[128];
  const int tid = threadIdx.x;
  const int r0  = blockIdx.x * 8;

  // cooperative load of 8 h-rows (8*512 floats = 1024 float4)
  for (int i = tid; i < 8 * (Hh / 4); i += 128) {
    const int row = i >> 7;          // /128
    const int c4  = i & 127;
    ((float4*)hs[row])[c4] =
        ((const float4*)(h2 + ((size_t)(r0 + row) * Hh)))[c4];
  }
  __syncthreads();

  const bool act = (tid < Cc);
  float acc[8];
  {
    const float bj = act ? bout[tid] : 0.f;
#pragma unroll
    for (int i = 0; i < 8; ++i) acc[i] = bj;
  }
  if (act) {
#pragma unroll 4
    for (int k = 0; k < Hh; ++k) {
      const float w = Wout[k * Cc + tid];
#pragma unroll
      for (int i = 0; i < 8; ++i) acc[i] = fmaf(hs[i][k], w, acc[i]);
    }
  }

  for (int row = 0; row < 8; ++row) {
    const float v = act ? acc[row] : -INFINITY;
    // block max
    red[tid] = v;
    __syncthreads();
    for (int s = 64; s > 0; s >>= 1) {
      if (tid < s) red[tid] = fmaxf(red[tid], red[tid + s]);
      __syncthreads();
    }
    const float mx = red[0];
    __syncthreads();
    const float e = act ? expf(v - mx) : 0.f;
    red[tid] = e;
    __syncthreads();
    for (int s = 64; s > 0; s >>= 1) {
      if (tid < s) red[tid] += red[tid + s];
      __syncthreads();
    }
    const float sum = red[0];
    __syncthreads();
    if (act) preds[(size_t)(r0 + row) * Cc + tid] = e / sum;
    const int lab = labels[r0 + row];
    if (tid == lab) ce[r0 + row] = logf(sum) + mx - v;
  }
}

__global__ __launch_bounds__(256)
void reduce_cost(const float* __restrict__ ce, float* __restrict__ out) {
  __shared__ float red[256];
  const int tid = threadIdx.x;
  float s = 0.f;
  for (int i = tid; i < ROWS; i += 256) s += ce[i];
  red[tid] = s;
  __syncthreads();
  for (int st = 128; st > 0; st >>= 1) {
    if (tid < st) red[tid] += red[tid + st];
    __syncthreads();
  }
  if (tid == 0) out[0] = red[0] / (float)Bb;
}

// ---------------- launch ----------------
extern "C" void kernel_launch(void* const* d_in, const int* in_sizes, int n_in,
                              void* d_out, int out_size, void* d_ws, size_t ws_size,
                              hipStream_t stream) {
  const float* inputs = (const float*)d_in[0];   // [B,T,D]
  const int*   labels = (const int*)d_in[1];     // [B,T]
  const float* W1     = (const float*)d_in[2];   // [D+H, 4H]
  const float* b1     = (const float*)d_in[3];   // [4H]
  const float* W2     = (const float*)d_in[4];   // [2H, 4H]
  const float* b2     = (const float*)d_in[5];   // [4H]
  const float* Wout   = (const float*)d_in[6];   // [H, C]
  const float* bout   = (const float*)d_in[7];   // [C]
  float* out = (float*)d_out;                    // preds [B,T,C] then cost

  float* ws   = (float*)d_ws;
  float* pre  = ws;                       // 8192*2048 (reused for layer 2)
  float* h1   = pre + (size_t)ROWS * Gg;  // 8192*512
  float* h2   = h1  + (size_t)ROWS * Hh;  // 8192*512
  float* c1   = h2  + (size_t)ROWS * Hh;  // 64*512
  float* c2   = c1  + (size_t)Bb * Hh;    // 64*512
  float* ceb  = c2  + (size_t)Bb * Hh;    // 8192

  const dim3 blk(256);
  const dim3 gemmGrid(Gg / BN, ROWS / BM);   // (16, 64)

  // Layer 1 input projection: pre = X @ W1[0:D,:] + b1
  sgemm_bias<<<gemmGrid, blk, 0, stream>>>(inputs, W1, b1, pre, ROWS, Gg, Dd);

  const float* W1h = W1 + (size_t)Dd * Gg;   // recurrent rows of W1
  for (int t = 0; t < Tt; ++t)
    lstm_step<<<128, 256, 0, stream>>>(pre, W1h, h1, c1, t);

  // Layer 2 input projection: pre = h1 @ W2[0:H,:] + b2
  sgemm_bias<<<gemmGrid, blk, 0, stream>>>(h1, W2, b2, pre, ROWS, Gg, Hh);

  const float* W2h = W2 + (size_t)Hh * Gg;   // recurrent rows of W2
  for (int t = 0; t < Tt; ++t)
    lstm_step<<<128, 256, 0, stream>>>(pre, W2h, h2, c2, t);

  proj_softmax<<<ROWS / 8, 128, 0, stream>>>(h2, Wout, bout, labels, out, ceb);
  reduce_cost<<<1, 256, 0, stream>>>(ceb, out + (size_t)ROWS * Cc);
}

// Round 2
// 3183.926 us; speedup vs baseline: 2.5731x; 2.5731x over previous
//
#include <hip/hip_runtime.h>
#include <cmath>

// Problem constants
#define Bb   64
#define Tt   128
#define Dd   2048
#define Hh   512
#define Gg   2048      // 4*H
#define Cc   101
#define ROWS 8192      // B*T

// ---------------- SGEMM (fp32, vector ALU) ----------------
// C[M,N] = A[M,K] @ B[K,N] + bias[N]
// 128x128 tile, BK=16, 256 threads, 8x8 per thread.
#define BM 128
#define BN 128
#define BK 16

__global__ __launch_bounds__(256)
void sgemm_bias(const float* __restrict__ A, const float* __restrict__ B,
                const float* __restrict__ bias, float* __restrict__ C,
                int M, int N, int K) {
  __shared__ float As[BK][BM];
  __shared__ float Bs[BK][BN];
  const int tid  = threadIdx.x;
  const int bn   = blockIdx.x;
  const int bm   = blockIdx.y;
  const int row0 = bm * BM, col0 = bn * BN;
  const int tr = (tid >> 4) << 3;   // (tid/16)*8
  const int tc = (tid & 15) << 3;   // (tid%16)*8

  float acc[8][8];
#pragma unroll
  for (int i = 0; i < 8; ++i)
#pragma unroll
    for (int j = 0; j < 8; ++j) acc[i][j] = 0.f;

  const int arow = tid >> 1;          // 0..127
  const int acol = (tid & 1) << 3;    // 0 or 8
  const int brow = tid >> 4;          // 0..15
  const int bcol = (tid & 15) << 3;   // 0..120
  const float* Ap = A + (size_t)(row0 + arow) * K + acol;
  const float* Bp = B + (size_t)brow * N + (col0 + bcol);

  for (int k0 = 0; k0 < K; k0 += BK) {
    const float4 a0 = *(const float4*)(Ap + k0);
    const float4 a1 = *(const float4*)(Ap + k0 + 4);
    const float4 bv0 = *(const float4*)(Bp + (size_t)k0 * N);
    const float4 bv1 = *(const float4*)(Bp + (size_t)k0 * N + 4);
    As[acol + 0][arow] = a0.x;
    As[acol + 1][arow] = a0.y;
    As[acol + 2][arow] = a0.z;
    As[acol + 3][arow] = a0.w;
    As[acol + 4][arow] = a1.x;
    As[acol + 5][arow] = a1.y;
    As[acol + 6][arow] = a1.z;
    As[acol + 7][arow] = a1.w;
    *(float4*)(&Bs[brow][bcol])     = bv0;
    *(float4*)(&Bs[brow][bcol + 4]) = bv1;
    __syncthreads();
#pragma unroll
    for (int k = 0; k < BK; ++k) {
      float a[8], b[8];
      *(float4*)(a)     = *(const float4*)(&As[k][tr]);
      *(float4*)(a + 4) = *(const float4*)(&As[k][tr + 4]);
      *(float4*)(b)     = *(const float4*)(&Bs[k][tc]);
      *(float4*)(b + 4) = *(const float4*)(&Bs[k][tc + 4]);
#pragma unroll
      for (int i = 0; i < 8; ++i)
#pragma unroll
        for (int j = 0; j < 8; ++j)
          acc[i][j] = fmaf(a[i], b[j], acc[i][j]);
    }
    __syncthreads();
  }

  float bj[8];
#pragma unroll
  for (int j = 0; j < 8; ++j) bj[j] = bias[col0 + tc + j];
#pragma unroll
  for (int i = 0; i < 8; ++i) {
    float* Cp = C + (size_t)(row0 + tr + i) * N + (col0 + tc);
    float4 o0, o1;
    o0.x = acc[i][0] + bj[0]; o0.y = acc[i][1] + bj[1];
    o0.z = acc[i][2] + bj[2]; o0.w = acc[i][3] + bj[3];
    o1.x = acc[i][4] + bj[4]; o1.y = acc[i][5] + bj[5];
    o1.z = acc[i][6] + bj[6]; o1.w = acc[i][7] + bj[7];
    *(float4*)(Cp)     = o0;
    *(float4*)(Cp + 4) = o1;
  }
}

// ---------------- LSTM recurrent step (v2) ----------------
// Grid: 256 blocks = 8 batch-groups x 32 col-groups; 256 threads.
// Block: batches b0..b0+7, m-indices m0..m0+15 (=> 64 gate-columns).
// Thread (ks, q): ks = K-split 16 ways, q = column-quad (g = q>>2, qi = q&3).
// Each thread accumulates 8 batches x 4 cols over its 32 k's (k = ks*4 + 64c + r).
__global__ __launch_bounds__(256)
void lstm_step2(const float* __restrict__ pre, const float* __restrict__ Wh,
                float* __restrict__ h_all, float* __restrict__ c_state,
                int t) {
  __shared__ float hs[8][Hh];          // 16 KB
  __shared__ float red[16][64][9];     // 36 KB (padded b-dim)
  const int tid = threadIdx.x;
  const int bg  = blockIdx.x >> 5;     // 0..7
  const int cg  = blockIdx.x & 31;     // 0..31
  const int b0  = bg * 8;
  const int m0  = cg * 16;
  const int ks  = tid >> 4;            // 0..15
  const int q   = tid & 15;            // 0..15
  const int g   = q >> 2;              // gate 0..3
  const int qi  = q & 3;               // quad-in-gate
  const int col = g * 512 + m0 + qi * 4;

  if (t > 0) {
    // stage h[t-1] for 8 batches into LDS (coalesced float4)
    for (int idx = tid; idx < 8 * (Hh / 4); idx += 256) {
      const int row = idx >> 7;        // 0..7
      const int c4  = idx & 127;
      *(float4*)(&hs[row][c4 * 4]) =
          *(const float4*)(h_all + ((size_t)(b0 + row) * Tt + (t - 1)) * Hh + c4 * 4);
    }
    __syncthreads();

    float acc[8][4];
#pragma unroll
    for (int b = 0; b < 8; ++b)
#pragma unroll
      for (int c = 0; c < 4; ++c) acc[b][c] = 0.f;

#pragma unroll 2
    for (int ch = 0; ch < 8; ++ch) {
      const int k = ks * 4 + ch * 64;  // 4 consecutive k's
      const float* Wp = Wh + (size_t)k * Gg + col;
      const float4 w0 = *(const float4*)(Wp);
      const float4 w1 = *(const float4*)(Wp + Gg);
      const float4 w2 = *(const float4*)(Wp + 2 * Gg);
      const float4 w3 = *(const float4*)(Wp + 3 * Gg);
#pragma unroll
      for (int b = 0; b < 8; ++b) {
        const float4 hv = *(const float4*)(&hs[b][k]);
        acc[b][0] = fmaf(hv.x, w0.x, fmaf(hv.y, w1.x, fmaf(hv.z, w2.x, fmaf(hv.w, w3.x, acc[b][0]))));
        acc[b][1] = fmaf(hv.x, w0.y, fmaf(hv.y, w1.y, fmaf(hv.z, w2.y, fmaf(hv.w, w3.y, acc[b][1]))));
        acc[b][2] = fmaf(hv.x, w0.z, fmaf(hv.y, w1.z, fmaf(hv.z, w2.z, fmaf(hv.w, w3.z, acc[b][2]))));
        acc[b][3] = fmaf(hv.x, w0.w, fmaf(hv.y, w1.w, fmaf(hv.z, w2.w, fmaf(hv.w, w3.w, acc[b][3]))));
      }
    }
    // write partials: red[ks][g*16 + qi*4 + c][b]
#pragma unroll
    for (int b = 0; b < 8; ++b)
#pragma unroll
      for (int c = 0; c < 4; ++c)
        red[ks][g * 16 + qi * 4 + c][b] = acc[b][c];
    __syncthreads();
  }

  // final: 128 threads each handle one (b, m_local)
  if (tid < 128) {
    const int b  = tid >> 4;           // 0..7
    const int ml = tid & 15;           // 0..15
    float i_s = 0.f, j_s = 0.f, f_s = 0.f, o_s = 0.f;
    if (t > 0) {
#pragma unroll
      for (int k = 0; k < 16; ++k) {
        i_s += red[k][ml][b];
        j_s += red[k][16 + ml][b];
        f_s += red[k][32 + ml][b];
        o_s += red[k][48 + ml][b];
      }
    }
    const int m = m0 + ml;
    const size_t prow = ((size_t)(b0 + b) * Tt + t) * (size_t)Gg + m;
    const float gi = pre[prow]        + i_s;
    const float gj = pre[prow + 512]  + j_s;
    const float gf = pre[prow + 1024] + f_s;
    const float go = pre[prow + 1536] + o_s;
    const float cp = (t > 0) ? c_state[(b0 + b) * Hh + m] : 0.f;
    const float si = 1.f / (1.f + expf(-gi));
    const float sf = 1.f / (1.f + expf(-(gf + 1.f)));   // forget bias 1.0
    const float so = 1.f / (1.f + expf(-go));
    const float nc = fmaf(cp, sf, si * tanhf(gj));
    const float nh = tanhf(nc) * so;
    c_state[(b0 + b) * Hh + m] = nc;
    h_all[((size_t)(b0 + b) * Tt + t) * Hh + m] = nh;
  }
}

// ---------------- Output projection + softmax + CE ----------------
// Block handles 8 rows; threads 0..100 each own one class column.
__global__ __launch_bounds__(128)
void proj_softmax(const float* __restrict__ h2, const float* __restrict__ Wout,
                  const float* __restrict__ bout, const int* __restrict__ labels,
                  float* __restrict__ preds, float* __restrict__ ce) {
  __shared__ float hs[8][Hh];
  __shared__ float wred[2][2];
  const int tid  = threadIdx.x;
  const int wid  = tid >> 6;
  const int r0   = blockIdx.x * 8;

  for (int i = tid; i < 8 * (Hh / 4); i += 128) {
    const int row = i >> 7;
    const int c4  = i & 127;
    ((float4*)hs[row])[c4] =
        ((const float4*)(h2 + ((size_t)(r0 + row) * Hh)))[c4];
  }
  __syncthreads();

  const bool act = (tid < Cc);
  float acc[8];
  {
    const float bj = act ? bout[tid] : 0.f;
#pragma unroll
    for (int i = 0; i < 8; ++i) acc[i] = bj;
  }
  if (act) {
#pragma unroll 4
    for (int k = 0; k < Hh; ++k) {
      const float w = Wout[k * Cc + tid];
#pragma unroll
      for (int i = 0; i < 8; ++i) acc[i] = fmaf(hs[i][k], w, acc[i]);
    }
  }

  for (int row = 0; row < 8; ++row) {
    const float v = act ? acc[row] : -INFINITY;
    float mw = v;
#pragma unroll
    for (int off = 32; off > 0; off >>= 1) mw = fmaxf(mw, __shfl_xor(mw, off));
    if ((tid & 63) == 0) wred[0][wid] = mw;
    __syncthreads();
    const float mx = fmaxf(wred[0][0], wred[0][1]);
    const float e = act ? expf(v - mx) : 0.f;
    float sw = e;
#pragma unroll
    for (int off = 32; off > 0; off >>= 1) sw += __shfl_xor(sw, off);
    if ((tid & 63) == 0) wred[1][wid] = sw;
    __syncthreads();
    const float sum = wred[1][0] + wred[1][1];
    if (act) preds[(size_t)(r0 + row) * Cc + tid] = e / sum;
    const int lab = labels[r0 + row];
    if (tid == lab) ce[r0 + row] = logf(sum) + mx - v;
    __syncthreads();  // protect wred before next row overwrites
  }
}

__global__ __launch_bounds__(256)
void reduce_cost(const float* __restrict__ ce, float* __restrict__ out) {
  __shared__ float red[256];
  const int tid = threadIdx.x;
  float s = 0.f;
  for (int i = tid; i < ROWS; i += 256) s += ce[i];
  red[tid] = s;
  __syncthreads();
  for (int st = 128; st > 0; st >>= 1) {
    if (tid < st) red[tid] += red[tid + st];
    __syncthreads();
  }
  if (tid == 0) out[0] = red[0] / (float)Bb;
}

// ---------------- launch ----------------
extern "C" void kernel_launch(void* const* d_in, const int* in_sizes, int n_in,
                              void* d_out, int out_size, void* d_ws, size_t ws_size,
                              hipStream_t stream) {
  const float* inputs = (const float*)d_in[0];   // [B,T,D]
  const int*   labels = (const int*)d_in[1];     // [B,T]
  const float* W1     = (const float*)d_in[2];   // [D+H, 4H]
  const float* b1     = (const float*)d_in[3];   // [4H]
  const float* W2     = (const float*)d_in[4];   // [2H, 4H]
  const float* b2     = (const float*)d_in[5];   // [4H]
  const float* Wout   = (const float*)d_in[6];   // [H, C]
  const float* bout   = (const float*)d_in[7];   // [C]
  float* out = (float*)d_out;                    // preds [B,T,C] then cost

  float* ws   = (float*)d_ws;
  float* pre  = ws;                       // 8192*2048 (reused for layer 2)
  float* h1   = pre + (size_t)ROWS * Gg;  // 8192*512
  float* h2   = h1  + (size_t)ROWS * Hh;  // 8192*512
  float* c1   = h2  + (size_t)ROWS * Hh;  // 64*512
  float* c2   = c1  + (size_t)Bb * Hh;    // 64*512
  float* ceb  = c2  + (size_t)Bb * Hh;    // 8192

  const dim3 blk(256);
  const dim3 gemmGrid(Gg / BN, ROWS / BM);   // (16, 64)

  // Layer 1 input projection: pre = X @ W1[0:D,:] + b1
  sgemm_bias<<<gemmGrid, blk, 0, stream>>>(inputs, W1, b1, pre, ROWS, Gg, Dd);

  const float* W1h = W1 + (size_t)Dd * Gg;   // recurrent rows of W1
  for (int t = 0; t < Tt; ++t)
    lstm_step2<<<256, 256, 0, stream>>>(pre, W1h, h1, c1, t);

  // Layer 2 input projection: pre = h1 @ W2[0:H,:] + b2
  sgemm_bias<<<gemmGrid, blk, 0, stream>>>(h1, W2, b2, pre, ROWS, Gg, Hh);

  const float* W2h = W2 + (size_t)Hh * Gg;   // recurrent rows of W2
  for (int t = 0; t < Tt; ++t)
    lstm_step2<<<256, 256, 0, stream>>>(pre, W2h, h2, c2, t);

  proj_softmax<<<ROWS / 8, 128, 0, stream>>>(h2, Wout, bout, labels, out, ceb);
  reduce_cost<<<1, 256, 0, stream>>>(ceb, out + (size_t)ROWS * Cc);
}